// Round 1
// baseline (732.068 us; speedup 1.0000x reference)
//
#include <hip/hip_runtime.h>
#include <hip/hip_bf16.h>
#include <stdint.h>

#define NB 8
#define NC 19
#define HC 32
#define WC 64
#define CF 256
#define HF 128
#define WF 256
#define HW 32768        // HF*WF
#define NPT 2048        // selected points per batch
#define KIN 275         // CF+NC
#define HID 256

__device__ __forceinline__ unsigned f2key(float f) {
  unsigned b = __float_as_uint(f);
  return (b & 0x80000000u) ? ~b : (b | 0x80000000u);
}

// ---------------------------------------------------------------- kernel 1
// bilinear upsample (align_corners) of coarse logits -> d_out, plus
// uncertainty = -(1/sum exp(l - max)) -> unc.  Arithmetic replicates the
// reference op-for-op (__f*_rn prevents fma contraction) because the top-k
// boundary is sensitive to ulp-level drift.
__global__ void k_upsample_uncert(const float* __restrict__ coarse,
                                  float* __restrict__ out,
                                  float* __restrict__ unc) {
  int gid = blockIdx.x * 256 + threadIdx.x;       // 0 .. NB*HW-1
  int b = gid >> 15;
  int pix = gid & (HW - 1);
  int y = pix >> 8;
  int x = pix & 255;
  const float sy = 31.0f / 127.0f;   // (HC-1)/(HF-1), f32 like jnp.linspace delta
  const float sx = 63.0f / 255.0f;
  float fy = __fmul_rn((float)y, sy);
  float fx = __fmul_rn((float)x, sx);
  int y0 = (int)floorf(fy); y0 = y0 < 0 ? 0 : (y0 > HC - 1 ? HC - 1 : y0);
  int x0 = (int)floorf(fx); x0 = x0 < 0 ? 0 : (x0 > WC - 1 ? WC - 1 : x0);
  int y1 = y0 + 1 > HC - 1 ? HC - 1 : y0 + 1;
  int x1 = x0 + 1 > WC - 1 ? WC - 1 : x0 + 1;
  float wy = __fsub_rn(fy, (float)y0);
  float wx = __fsub_rn(fx, (float)x0);
  float omy = __fsub_rn(1.0f, wy);
  float omx = __fsub_rn(1.0f, wx);
  const float* cb = coarse + (size_t)b * NC * (HC * WC);
  float li[NC];
  float m = -1e30f;
  #pragma unroll
  for (int c = 0; c < NC; c++) {
    const float* cp = cb + c * (HC * WC);
    float v00 = cp[y0 * WC + x0], v01 = cp[y0 * WC + x1];
    float v10 = cp[y1 * WC + x0], v11 = cp[y1 * WC + x1];
    // rows = x[y0]*(1-wy) + x[y1]*wy ; out = rows[x0]*(1-wx) + rows[x1]*wx
    float a0 = __fadd_rn(__fmul_rn(v00, omy), __fmul_rn(v10, wy));
    float a1 = __fadd_rn(__fmul_rn(v01, omy), __fmul_rn(v11, wy));
    float v  = __fadd_rn(__fmul_rn(a0, omx), __fmul_rn(a1, wx));
    li[c] = v;
    m = fmaxf(m, v);
    out[(((size_t)b * NC + c) << 15) + pix] = v;
  }
  float s = 0.0f;
  #pragma unroll
  for (int c = 0; c < NC; c++) s = __fadd_rn(s, expf(__fsub_rn(li[c], m)));
  unc[gid] = -__fdiv_rn(1.0f, s);   // = -max(softmax)
}

// ---------------------------------------------------------------- kernel 2
// exact top-NPT per batch: 4-pass byte radix select + stable tie resolution
__global__ void k_topk(const float* __restrict__ unc, unsigned* __restrict__ pidx) {
  int b = blockIdx.x;
  int tid = threadIdx.x;
  const float* ub = unc + b * HW;
  __shared__ int cnt[256];
  __shared__ int wsum[4];
  __shared__ unsigned sh_pref;
  __shared__ int sh_k;
  __shared__ int g_cnt, e_cnt;
  __shared__ int eqlist[3072];

  unsigned pref = 0;
  int k = NPT;
  for (int pass = 0; pass < 4; pass++) {
    int sh = 24 - pass * 8;
    cnt[tid] = 0;
    __syncthreads();
    for (int j = 0; j < HW / 256; j++) {
      unsigned key = f2key(ub[tid + j * 256]);
      bool match = true;
      if (pass > 0) match = ((key >> (sh + 8)) == pref);
      if (match) atomicAdd(&cnt[(key >> sh) & 255], 1);
    }
    __syncthreads();
    // suffix selection: thread tid handles byte v = 255 - tid
    int v = 255 - tid;
    int val = cnt[v];
    int lane = tid & 63, w = tid >> 6;
    int xs = val;
    #pragma unroll
    for (int d = 1; d < 64; d <<= 1) {
      int yv = __shfl_up(xs, d, 64);
      if (lane >= d) xs += yv;
    }
    if (lane == 63) wsum[w] = xs;
    __syncthreads();
    int base = 0;
    for (int i = 0; i < w; i++) base += wsum[i];
    int incl = xs + base;         // # elems with byte >= v (among matching)
    int S = incl - val;           // # elems with byte >  v
    if (S < k && k <= incl) {
      sh_pref = (pref << 8) | (unsigned)v;
      sh_k = k - S;
    }
    __syncthreads();
    pref = sh_pref;
    k = sh_k;
    __syncthreads();
  }
  unsigned T = pref;  // exact key of the NPT-th largest
  int keq = k;        // how many ==T to take (lowest indices)
  int G = NPT - keq;
  if (tid == 0) { g_cnt = 0; e_cnt = 0; }
  __syncthreads();
  unsigned* pb = pidx + b * NPT;
  for (int j = 0; j < HW / 256; j++) {
    int idx = tid + j * 256;
    unsigned key = f2key(ub[idx]);
    if (key > T) {
      int s = atomicAdd(&g_cnt, 1);
      pb[s] = (unsigned)idx;
    } else if (key == T) {
      int e = atomicAdd(&e_cnt, 1);
      if (e < 3072) eqlist[e] = idx;
    }
  }
  __syncthreads();
  int E = e_cnt; if (E > 3072) E = 3072;
  if (E == keq) {
    for (int i = tid; i < keq; i += 256) pb[G + i] = (unsigned)eqlist[i];
  } else {
    for (int i = tid; i < E; i += 256) {
      int pi = eqlist[i];
      int r = 0;
      for (int j2 = 0; j2 < E; j2++) r += (eqlist[j2] < pi) ? 1 : 0;
      if (r < keq) pb[G + r] = (unsigned)pi;   // keq smallest indices win
    }
  }
}

// ---------------------------------------------------------------- kernel 3
// transpose w1,w2 for coalesced GEMM loads
__global__ void k_transpose(const float* __restrict__ w1, const float* __restrict__ w2,
                            float* __restrict__ w1T, float* __restrict__ w2T) {
  int gid = blockIdx.x * 256 + threadIdx.x;
  if (gid < KIN * HID) {
    int kk = gid >> 8, o = gid & 255;
    w1T[gid] = w1[o * KIN + kk];
  } else {
    int g2 = gid - KIN * HID;
    if (g2 < HID * HID) {
      int kk = g2 >> 8, o = g2 & 255;
      w2T[g2] = w2[o * HID + kk];
    }
  }
}

// ---------------------------------------------------------------- kernel 4
// gather point features: stream one (b,c) half-image into LDS (coalesced,
// ~1.0x image traffic) then bilinear-sample the 2048 points from LDS.
// c<CF: fine_features; c>=CF: coarse_up (d_out). Output pfT[b][c][p].
__global__ void k_gather(const float* __restrict__ fine,
                         const float* __restrict__ cup,
                         const unsigned* __restrict__ pidx,
                         float* __restrict__ pfT) {
  int c = blockIdx.x;   // 0..KIN-1
  int b = blockIdx.y;
  int h = blockIdx.z;   // image half by y0
  int tid = threadIdx.x;
  const float* src = (c < CF) ? (fine + (((size_t)b * CF + c) << 15))
                              : (cup + (((size_t)b * NC + (c - CF)) << 15));
  __shared__ float img[65 * 256];
  int r0 = h * 64;
  int nrows = (h == 0) ? 65 : 64;   // +1 boundary row for y1
  const float4* s4 = (const float4*)(src + r0 * 256);
  float4* i4 = (float4*)img;
  for (int i = tid; i < nrows * 64; i += 256) i4[i] = s4[i];
  __syncthreads();
  float* dst = pfT + ((size_t)b * KIN + c) * NPT;
  const unsigned* pb = pidx + b * NPT;
  for (int j = 0; j < NPT / 256; j++) {
    int p = tid + j * 256;
    int pix = (int)pb[p];
    int px = pix & 255, py = pix >> 8;
    // replicate reference coord math (tolerance-level; no selection downstream)
    float vx = (float)px / 255.0f * 2.0f - 1.0f;
    float vy = (float)py / 127.0f * 2.0f - 1.0f;
    float ix = (vx + 1.0f) * 0.5f * 255.0f;
    float iy = (vy + 1.0f) * 0.5f * 127.0f;
    int x0 = (int)floorf(ix); x0 = x0 < 0 ? 0 : (x0 > WF - 1 ? WF - 1 : x0);
    int y0 = (int)floorf(iy); y0 = y0 < 0 ? 0 : (y0 > HF - 1 ? HF - 1 : y0);
    if (y0 < r0 || y0 >= r0 + 64) continue;
    int x1 = x0 + 1 > WF - 1 ? WF - 1 : x0 + 1;
    int y1 = y0 + 1 > HF - 1 ? HF - 1 : y0 + 1;
    float wx = ix - (float)x0, wy = iy - (float)y0;
    float omx = 1.0f - wx, omy = 1.0f - wy;
    float g00 = img[(y0 - r0) * 256 + x0], g01 = img[(y0 - r0) * 256 + x1];
    float g10 = img[(y1 - r0) * 256 + x0], g11 = img[(y1 - r0) * 256 + x1];
    float r = ((g00 * omx) * omy + (g01 * wx) * omy)
            + (g10 * omx) * wy + (g11 * wx) * wy;
    dst[p] = r;
  }
}

// ---------------------------------------------------------------- kernel 5/6
// f32 SGEMM: outT[b][o][p] = act(WT^T @ inT + bias). Tile 64x128, micro 4x8.
template<int KDIM, bool RELU>
__global__ void k_gemm(const float* __restrict__ WT, const float* __restrict__ bias,
                       const float* __restrict__ inT, float* __restrict__ outT) {
  __shared__ float Wl[8][64];
  __shared__ float Bl[8][128];
  int nt = blockIdx.x, ot = blockIdx.y, b = blockIdx.z;
  int tid = threadIdx.x;
  int tg_o = tid >> 4, tg_n = tid & 15;
  const float* inB = inT + (size_t)b * KDIM * NPT + nt * 128;
  const float* WTo = WT + ot * 64;
  float acc[4][8];
  #pragma unroll
  for (int a = 0; a < 4; a++)
    #pragma unroll
    for (int e = 0; e < 8; e++) acc[a][e] = 0.f;
  for (int k0 = 0; k0 < KDIM; k0 += 8) {
    #pragma unroll
    for (int r2 = 0; r2 < 2; r2++) {
      int idx = tid + r2 * 256, kk = idx >> 6, o = idx & 63;
      Wl[kk][o] = (k0 + kk < KDIM) ? WTo[(k0 + kk) * HID + o] : 0.f;
    }
    #pragma unroll
    for (int r4 = 0; r4 < 4; r4++) {
      int idx = tid + r4 * 256, kk = idx >> 7, n = idx & 127;
      Bl[kk][n] = (k0 + kk < KDIM) ? inB[(size_t)(k0 + kk) * NPT + n] : 0.f;
    }
    __syncthreads();
    #pragma unroll
    for (int kk = 0; kk < 8; kk++) {
      float wv[4], bv[8];
      #pragma unroll
      for (int a = 0; a < 4; a++) wv[a] = Wl[kk][tg_o * 4 + a];
      #pragma unroll
      for (int e = 0; e < 8; e++) bv[e] = Bl[kk][tg_n * 8 + e];
      #pragma unroll
      for (int a = 0; a < 4; a++)
        #pragma unroll
        for (int e = 0; e < 8; e++) acc[a][e] += wv[a] * bv[e];
    }
    __syncthreads();
  }
  #pragma unroll
  for (int a = 0; a < 4; a++) {
    int o = ot * 64 + tg_o * 4 + a;
    float bb = bias[o];
    #pragma unroll
    for (int e = 0; e < 8; e++) {
      float v = acc[a][e] + bb;
      if (RELU) v = fmaxf(v, 0.f);
      outT[((size_t)b * HID + o) * NPT + nt * 128 + tg_n * 8 + e] = v;
    }
  }
}

// ---------------------------------------------------------------- kernel 7
// layer-3 (19 outs) + scatter refined logits into d_out at selected pixels
__global__ void k_mlp3_scatter(const float* __restrict__ w3, const float* __restrict__ b3,
                               const float* __restrict__ h2T, const unsigned* __restrict__ pidx,
                               float* __restrict__ out) {
  __shared__ float h2l[256][64];
  __shared__ float w3l[NC * 256];
  int p0 = blockIdx.x * 64, b = blockIdx.y, tid = threadIdx.x;
  const float* hb = h2T + (size_t)b * HID * NPT + p0;
  float4* d4 = (float4*)(&h2l[0][0]);
  for (int i = tid; i < 256 * 16; i += 256) {
    int kk = i >> 4, q = i & 15;
    d4[i] = *(const float4*)(hb + (size_t)kk * NPT + q * 4);
  }
  for (int i = tid; i < NC * 64; i += 256) ((float4*)w3l)[i] = ((const float4*)w3)[i];
  __syncthreads();
  int p = tid & 63, og = tid >> 6;
  int pix = (int)pidx[b * NPT + p0 + p];
  for (int o = og; o < NC; o += 4) {
    float acc = 0.f;
    #pragma unroll 8
    for (int kk = 0; kk < 256; kk++) acc += w3l[o * 256 + kk] * h2l[kk][p];
    out[(((size_t)b * NC + o) << 15) + pix] = acc + b3[o];
  }
}

// ----------------------------------------------------------------
extern "C" void kernel_launch(void* const* d_in, const int* in_sizes, int n_in,
                              void* d_out, int out_size, void* d_ws, size_t ws_size,
                              hipStream_t stream) {
  const float* coarse = (const float*)d_in[0];
  const float* fine   = (const float*)d_in[1];
  const float* w1 = (const float*)d_in[2];
  const float* b1 = (const float*)d_in[3];
  const float* w2 = (const float*)d_in[4];
  const float* b2 = (const float*)d_in[5];
  const float* w3 = (const float*)d_in[6];
  const float* b3 = (const float*)d_in[7];
  float* out = (float*)d_out;
  char* ws = (char*)d_ws;
  // workspace layout (bytes):
  float*    unc  = (float*)ws;                     //  1,048,576
  unsigned* pidx = (unsigned*)(ws + 1048576);      //     65,536
  float*    w1T  = (float*)(ws + 1114112);         //    281,600
  float*    w2T  = (float*)(ws + 1395712);         //    262,144
  float*    pfT  = (float*)(ws + 1657856);         // 18,022,400
  float*    h1T  = (float*)(ws + 19680256);        // 16,777,216 (end 36,457,472)
  float*    h2T  = pfT;                            // pf dead after layer 1

  k_upsample_uncert<<<dim3(NB * HW / 256), 256, 0, stream>>>(coarse, out, unc);
  k_topk<<<dim3(NB), 256, 0, stream>>>(unc, pidx);
  k_transpose<<<dim3((KIN * HID + HID * HID + 255) / 256), 256, 0, stream>>>(w1, w2, w1T, w2T);
  k_gather<<<dim3(KIN, NB, 2), 256, 0, stream>>>(fine, out, pidx, pfT);
  k_gemm<KIN, true><<<dim3(16, 4, NB), 256, 0, stream>>>(w1T, b1, pfT, h1T);
  k_gemm<HID, true><<<dim3(16, 4, NB), 256, 0, stream>>>(w2T, b2, h1T, h2T);
  k_mlp3_scatter<<<dim3(NPT / 64, NB), 256, 0, stream>>>(w3, b3, h2T, pidx, out);
}

// Round 2
// 584.004 us; speedup vs baseline: 1.2535x; 1.2535x over previous
//
#include <hip/hip_runtime.h>
#include <hip/hip_bf16.h>
#include <stdint.h>

#define NB 8
#define NC 19
#define HC 32
#define WC 64
#define CF 256
#define HF 128
#define WF 256
#define HW 32768        // HF*WF
#define NPT 2048        // selected points per batch
#define KIN 275         // CF+NC
#define KPAD 280        // KIN padded to multiple of 8 (zero rows)
#define HID 256

__device__ __forceinline__ unsigned f2key(float f) {
  unsigned b = __float_as_uint(f);
  return (b & 0x80000000u) ? ~b : (b | 0x80000000u);
}

__device__ __forceinline__ void gload16(const float* g, float* l) {
  __builtin_amdgcn_global_load_lds((const __attribute__((address_space(1))) void*)g,
                                   (__attribute__((address_space(3))) void*)l, 16, 0, 0);
}

// ---------------------------------------------------------------- kernel 1
// bilinear upsample (align_corners) of coarse logits -> d_out, plus
// uncertainty = -(1/sum exp(l - max)) -> unc.  _rn ops prevent fma
// contraction: top-k selection boundary is ulp-sensitive.
__global__ void k_upsample_uncert(const float* __restrict__ coarse,
                                  float* __restrict__ out,
                                  float* __restrict__ unc) {
  int gid = blockIdx.x * 256 + threadIdx.x;       // 0 .. NB*HW-1
  int b = gid >> 15;
  int pix = gid & (HW - 1);
  int y = pix >> 8;
  int x = pix & 255;
  const float sy = 31.0f / 127.0f;
  const float sx = 63.0f / 255.0f;
  float fy = __fmul_rn((float)y, sy);
  float fx = __fmul_rn((float)x, sx);
  int y0 = (int)floorf(fy); y0 = y0 < 0 ? 0 : (y0 > HC - 1 ? HC - 1 : y0);
  int x0 = (int)floorf(fx); x0 = x0 < 0 ? 0 : (x0 > WC - 1 ? WC - 1 : x0);
  int y1 = y0 + 1 > HC - 1 ? HC - 1 : y0 + 1;
  int x1 = x0 + 1 > WC - 1 ? WC - 1 : x0 + 1;
  float wy = __fsub_rn(fy, (float)y0);
  float wx = __fsub_rn(fx, (float)x0);
  float omy = __fsub_rn(1.0f, wy);
  float omx = __fsub_rn(1.0f, wx);
  const float* cb = coarse + (size_t)b * NC * (HC * WC);
  float li[NC];
  float m = -1e30f;
  #pragma unroll
  for (int c = 0; c < NC; c++) {
    const float* cp = cb + c * (HC * WC);
    float v00 = cp[y0 * WC + x0], v01 = cp[y0 * WC + x1];
    float v10 = cp[y1 * WC + x0], v11 = cp[y1 * WC + x1];
    float a0 = __fadd_rn(__fmul_rn(v00, omy), __fmul_rn(v10, wy));
    float a1 = __fadd_rn(__fmul_rn(v01, omy), __fmul_rn(v11, wy));
    float v  = __fadd_rn(__fmul_rn(a0, omx), __fmul_rn(a1, wx));
    li[c] = v;
    m = fmaxf(m, v);
    out[(((size_t)b * NC + c) << 15) + pix] = v;
  }
  float s = 0.0f;
  #pragma unroll
  for (int c = 0; c < NC; c++) s = __fadd_rn(s, expf(__fsub_rn(li[c], m)));
  unc[gid] = -__fdiv_rn(1.0f, s);
}

// ---------------------------------------------------------------- top-k
// parallel 3-level radix select: bits [31:21], [20:10], [9:0].
// suffix_select: find bin t with cnt(>t) < k <= cnt(>=t); krem = k - cnt(>t).
template<int NBINS>
__device__ void suffix_select(const int* __restrict__ gh, int k, int tid,
                              int* ssum, int* res) {
  const int C = NBINS / 256;
  int h[8];
  int s = 0;
  #pragma unroll
  for (int j = 0; j < C; j++) { h[j] = gh[tid * C + j]; s += h[j]; }
  ssum[tid] = s;
  __syncthreads();
  for (int off = 1; off < 256; off <<= 1) {
    int v = ssum[tid] + ((tid + off < 256) ? ssum[tid + off] : 0);
    __syncthreads();
    ssum[tid] = v;
    __syncthreads();
  }
  int S = ssum[tid] - s;          // count strictly above my chunk
  #pragma unroll
  for (int j = C - 1; j >= 0; j--) {
    int c = h[j];
    if (S < k && k <= S + c) { res[0] = tid * C + j; res[1] = k - S; }
    S += c;
  }
  __syncthreads();
}

__global__ void k_hist1(const float* __restrict__ unc, int* __restrict__ hist1) {
  __shared__ int lh[2048];
  int b = blockIdx.x, chunk = blockIdx.y, tid = threadIdx.x;
  for (int i = tid; i < 2048; i += 256) lh[i] = 0;
  __syncthreads();
  const float* ub = unc + b * HW + chunk * 2048;
  #pragma unroll
  for (int j = 0; j < 8; j++) {
    unsigned key = f2key(ub[tid + j * 256]);
    atomicAdd(&lh[key >> 21], 1);
  }
  __syncthreads();
  int* gh = hist1 + b * 2048;
  for (int i = tid; i < 2048; i += 256) { int v = lh[i]; if (v) atomicAdd(&gh[i], v); }
}

__global__ void k_hist2(const float* __restrict__ unc, const int* __restrict__ hist1,
                        int* __restrict__ hist2) {
  __shared__ int lh[2048];
  __shared__ int ssum[256];
  __shared__ int res[2];
  int b = blockIdx.x, chunk = blockIdx.y, tid = threadIdx.x;
  suffix_select<2048>(hist1 + b * 2048, NPT, tid, ssum, res);
  int t1 = res[0];
  for (int i = tid; i < 2048; i += 256) lh[i] = 0;
  __syncthreads();
  const float* ub = unc + b * HW + chunk * 2048;
  #pragma unroll
  for (int j = 0; j < 8; j++) {
    unsigned key = f2key(ub[tid + j * 256]);
    if ((int)(key >> 21) == t1) atomicAdd(&lh[(key >> 10) & 2047], 1);
  }
  __syncthreads();
  int* gh = hist2 + b * 2048;
  for (int i = tid; i < 2048; i += 256) { int v = lh[i]; if (v) atomicAdd(&gh[i], v); }
}

__global__ void k_hist3(const float* __restrict__ unc, const int* __restrict__ hist1,
                        const int* __restrict__ hist2, int* __restrict__ hist3) {
  __shared__ int lh[1024];
  __shared__ int ssum[256];
  __shared__ int res[2];
  int b = blockIdx.x, chunk = blockIdx.y, tid = threadIdx.x;
  suffix_select<2048>(hist1 + b * 2048, NPT, tid, ssum, res);
  int t1 = res[0], k1 = res[1];
  __syncthreads();
  suffix_select<2048>(hist2 + b * 2048, k1, tid, ssum, res);
  int t2 = res[0];
  unsigned pref22 = ((unsigned)t1 << 11) | (unsigned)t2;
  for (int i = tid; i < 1024; i += 256) lh[i] = 0;
  __syncthreads();
  const float* ub = unc + b * HW + chunk * 2048;
  #pragma unroll
  for (int j = 0; j < 8; j++) {
    unsigned key = f2key(ub[tid + j * 256]);
    if ((key >> 10) == pref22) atomicAdd(&lh[key & 1023], 1);
  }
  __syncthreads();
  int* gh = hist3 + b * 1024;
  for (int i = tid; i < 1024; i += 256) { int v = lh[i]; if (v) atomicAdd(&gh[i], v); }
}

__global__ void k_select(const float* __restrict__ unc, const int* __restrict__ hist1,
                         const int* __restrict__ hist2, const int* __restrict__ hist3,
                         int* __restrict__ cnts, int* __restrict__ eq,
                         unsigned* __restrict__ pidx) {
  __shared__ int ssum[256];
  __shared__ int res[2];
  __shared__ int gbuf[2048];
  __shared__ int ebuf[2048];
  __shared__ int lcntG, lcntE, lbaseG, lbaseE;
  int b = blockIdx.x, chunk = blockIdx.y, tid = threadIdx.x;
  suffix_select<2048>(hist1 + b * 2048, NPT, tid, ssum, res);
  int t1 = res[0], k1 = res[1];
  __syncthreads();
  suffix_select<2048>(hist2 + b * 2048, k1, tid, ssum, res);
  int t2 = res[0], k2 = res[1];
  __syncthreads();
  suffix_select<1024>(hist3 + b * 1024, k2, tid, ssum, res);
  int t3 = res[0], keq = res[1];
  unsigned T = ((unsigned)t1 << 21) | ((unsigned)t2 << 10) | (unsigned)t3;
  if (chunk == 0 && tid == 0) cnts[16 + b] = keq;
  if (tid == 0) { lcntG = 0; lcntE = 0; }
  __syncthreads();
  const float* ub = unc + b * HW;
  int base = chunk * 2048;
  #pragma unroll
  for (int j = 0; j < 8; j++) {
    int idx = base + tid + j * 256;
    unsigned key = f2key(ub[idx]);
    if (key > T)       { int s = atomicAdd(&lcntG, 1); gbuf[s] = idx; }
    else if (key == T) { int e = atomicAdd(&lcntE, 1); ebuf[e] = idx; }
  }
  __syncthreads();
  if (tid == 0) {
    lbaseG = atomicAdd(&cnts[b], lcntG);
    lbaseE = atomicAdd(&cnts[8 + b], lcntE);
  }
  __syncthreads();
  unsigned* pb = pidx + b * NPT;
  for (int i = tid; i < lcntG; i += 256) pb[lbaseG + i] = (unsigned)gbuf[i];
  for (int i = tid; i < lcntE; i += 256) {
    int s = lbaseE + i;
    if (s < 4096) eq[b * 4096 + s] = ebuf[i];
  }
}

__global__ void k_ties(const int* __restrict__ cnts, const int* __restrict__ eq,
                       unsigned* __restrict__ pidx) {
  int b = blockIdx.x, tid = threadIdx.x;
  int E = cnts[8 + b]; if (E > 4096) E = 4096;
  int keq = cnts[16 + b];
  int G = NPT - keq;
  unsigned* pb = pidx + b * NPT;
  const int* el = eq + b * 4096;
  if (E == keq) {
    for (int i = tid; i < keq; i += 256) pb[G + i] = (unsigned)el[i];
  } else {
    for (int i = tid; i < E; i += 256) {
      int pi = el[i];
      int r = 0;
      for (int j = 0; j < E; j++) r += (el[j] < pi) ? 1 : 0;
      if (r < keq) pb[G + r] = (unsigned)pi;   // keq smallest indices win
    }
  }
}

// ---------------------------------------------------------------- kernel 3
// transpose w1,w2 -> k-major; zero-pad w1T rows KIN..KPAD
__global__ void k_transpose(const float* __restrict__ w1, const float* __restrict__ w2,
                            float* __restrict__ w1T, float* __restrict__ w2T) {
  int gid = blockIdx.x * 256 + threadIdx.x;
  if (gid < KPAD * HID) {
    int kk = gid >> 8, o = gid & 255;
    w1T[gid] = (kk < KIN) ? w1[o * KIN + kk] : 0.f;
  } else {
    int g2 = gid - KPAD * HID;
    if (g2 < HID * HID) {
      int kk = g2 >> 8, o = g2 & 255;
      w2T[g2] = w2[o * HID + kk];
    }
  }
}

// ---------------------------------------------------------------- kernel 4
// gather point features: stream one (b,c) half-image into LDS (coalesced)
// then bilinear-sample the 2048 points from LDS.  _rn ops replicate the
// reference coord arithmetic bit-exactly (floor boundaries!).
__global__ void k_gather(const float* __restrict__ fine,
                         const float* __restrict__ cup,
                         const unsigned* __restrict__ pidx,
                         float* __restrict__ pfT) {
  int c = blockIdx.x;   // 0..KPAD-1
  int b = blockIdx.y;
  int h = blockIdx.z;
  int tid = threadIdx.x;
  float* dst = pfT + ((size_t)b * KPAD + c) * NPT;
  if (c >= KIN) {       // zero pad rows
    if (h == 0) for (int p = tid; p < NPT; p += 256) dst[p] = 0.f;
    return;
  }
  const float* src = (c < CF) ? (fine + (((size_t)b * CF + c) << 15))
                              : (cup + (((size_t)b * NC + (c - CF)) << 15));
  __shared__ float img[65 * 256];
  int r0 = h * 64;
  int nrows = (h == 0) ? 65 : 64;
  const float4* s4 = (const float4*)(src + r0 * 256);
  float4* i4 = (float4*)img;
  for (int i = tid; i < nrows * 64; i += 256) i4[i] = s4[i];
  __syncthreads();
  const unsigned* pb = pidx + b * NPT;
  for (int j = 0; j < NPT / 256; j++) {
    int p = tid + j * 256;
    int pix = (int)pb[p];
    int px = pix & 255, py = pix >> 8;
    // reference: v = idx/(dim-1)*2-1 ; i = (v+1)*0.5*(dim-1), no contraction
    float tx = __fdiv_rn((float)px, 255.0f);
    float vx = __fsub_rn(__fmul_rn(tx, 2.0f), 1.0f);
    float ix = __fmul_rn(__fmul_rn(__fadd_rn(vx, 1.0f), 0.5f), 255.0f);
    float ty = __fdiv_rn((float)py, 127.0f);
    float vy = __fsub_rn(__fmul_rn(ty, 2.0f), 1.0f);
    float iy = __fmul_rn(__fmul_rn(__fadd_rn(vy, 1.0f), 0.5f), 127.0f);
    int x0 = (int)floorf(ix); x0 = x0 < 0 ? 0 : (x0 > WF - 1 ? WF - 1 : x0);
    int y0 = (int)floorf(iy); y0 = y0 < 0 ? 0 : (y0 > HF - 1 ? HF - 1 : y0);
    if (y0 < r0 || y0 >= r0 + 64) continue;
    int x1 = x0 + 1 > WF - 1 ? WF - 1 : x0 + 1;
    int y1 = y0 + 1 > HF - 1 ? HF - 1 : y0 + 1;
    float wx = __fsub_rn(ix, (float)x0), wy = __fsub_rn(iy, (float)y0);
    float omx = __fsub_rn(1.0f, wx), omy = __fsub_rn(1.0f, wy);
    float g00 = img[(y0 - r0) * 256 + x0], g01 = img[(y0 - r0) * 256 + x1];
    float g10 = img[(y1 - r0) * 256 + x0], g11 = img[(y1 - r0) * 256 + x1];
    float a_ = __fmul_rn(__fmul_rn(g00, omx), omy);
    float b_ = __fmul_rn(__fmul_rn(g01, wx), omy);
    float c_ = __fmul_rn(__fmul_rn(g10, omx), wy);
    float d_ = __fmul_rn(__fmul_rn(g11, wx), wy);
    dst[p] = __fadd_rn(__fadd_rn(__fadd_rn(a_, b_), c_), d_);
  }
}

// ---------------------------------------------------------------- kernel 5/6
// f32 SGEMM, 128x128 tile, 8x8 micro, global_load_lds dbuf staging,
// raw s_barrier + vmcnt(0) AFTER compute (prefetch flies under FMAs).
template<int KDIM, bool RELU>
__global__ __launch_bounds__(256) void k_gemm(const float* __restrict__ WT,
                                              const float* __restrict__ bias,
                                              const float* __restrict__ inT,
                                              float* __restrict__ outT) {
  __shared__ float Wl[2][8][128];
  __shared__ float Bl[2][8][128];
  int nt = blockIdx.x, ot = blockIdx.y, b = blockIdx.z;
  int tid = threadIdx.x;
  int tg_o = tid >> 4, tg_n = tid & 15;
  int lane = tid & 63, wvi = tid >> 6;
  int skk = wvi * 2 + (lane >> 5);
  int scol = (lane & 31) * 4;
  const float* gW = WT + ot * 128 + skk * HID + scol;
  const float* gB = inT + (size_t)b * KDIM * NPT + nt * 128 + (size_t)skk * NPT + scol;
  float* ldsW0 = &Wl[0][0][0] + wvi * 256;
  float* ldsB0 = &Bl[0][0][0] + wvi * 256;
  float* ldsW1 = &Wl[1][0][0] + wvi * 256;
  float* ldsB1 = &Bl[1][0][0] + wvi * 256;

  float acc[8][8];
  #pragma unroll
  for (int a = 0; a < 8; a++)
    #pragma unroll
    for (int e = 0; e < 8; e++) acc[a][e] = 0.f;

  constexpr int T = KDIM / 8;
  // prologue: stage tile 0 into buf 0
  gload16(gW, ldsW0);
  gload16(gB, ldsB0);
  asm volatile("s_waitcnt vmcnt(0)" ::: "memory");
  __builtin_amdgcn_s_barrier();

  for (int t = 0; t < T; t++) {
    int cur = t & 1;
    if (t + 1 < T) {   // stage next tile into other buffer (flies under FMAs)
      gload16(gW + (size_t)(t + 1) * 8 * HID, cur ? ldsW0 : ldsW1);
      gload16(gB + (size_t)(t + 1) * 8 * NPT, cur ? ldsB0 : ldsB1);
    }
    #pragma unroll
    for (int kk = 0; kk < 8; kk++) {
      const float* wrow = &Wl[cur][kk][tg_o * 8];
      const float* brow = &Bl[cur][kk][tg_n * 8];
      float4 w0 = *(const float4*)wrow, w1v = *(const float4*)(wrow + 4);
      float4 b0 = *(const float4*)brow, b1v = *(const float4*)(brow + 4);
      float wv8[8] = {w0.x, w0.y, w0.z, w0.w, w1v.x, w1v.y, w1v.z, w1v.w};
      float bv8[8] = {b0.x, b0.y, b0.z, b0.w, b1v.x, b1v.y, b1v.z, b1v.w};
      #pragma unroll
      for (int a = 0; a < 8; a++)
        #pragma unroll
        for (int e = 0; e < 8; e++) acc[a][e] += wv8[a] * bv8[e];
    }
    asm volatile("s_waitcnt vmcnt(0)" ::: "memory");
    __builtin_amdgcn_s_barrier();
  }

  #pragma unroll
  for (int a = 0; a < 8; a++) {
    int o = ot * 128 + tg_o * 8 + a;
    float bb = bias[o];
    float* dst = outT + ((size_t)b * HID + o) * NPT + nt * 128 + tg_n * 8;
    float4 r0, r1;
    r0.x = acc[a][0] + bb; r0.y = acc[a][1] + bb; r0.z = acc[a][2] + bb; r0.w = acc[a][3] + bb;
    r1.x = acc[a][4] + bb; r1.y = acc[a][5] + bb; r1.z = acc[a][6] + bb; r1.w = acc[a][7] + bb;
    if (RELU) {
      r0.x = fmaxf(r0.x, 0.f); r0.y = fmaxf(r0.y, 0.f); r0.z = fmaxf(r0.z, 0.f); r0.w = fmaxf(r0.w, 0.f);
      r1.x = fmaxf(r1.x, 0.f); r1.y = fmaxf(r1.y, 0.f); r1.z = fmaxf(r1.z, 0.f); r1.w = fmaxf(r1.w, 0.f);
    }
    *(float4*)dst = r0;
    *(float4*)(dst + 4) = r1;
  }
}

// ---------------------------------------------------------------- kernel 7
// layer-3 (19 outs) + scatter refined logits into d_out at selected pixels
__global__ void k_mlp3_scatter(const float* __restrict__ w3, const float* __restrict__ b3,
                               const float* __restrict__ h2T, const unsigned* __restrict__ pidx,
                               float* __restrict__ out) {
  __shared__ float h2l[256][64];
  __shared__ float w3l[NC * 256];
  int p0 = blockIdx.x * 64, b = blockIdx.y, tid = threadIdx.x;
  const float* hb = h2T + (size_t)b * HID * NPT + p0;
  float4* d4 = (float4*)(&h2l[0][0]);
  for (int i = tid; i < 256 * 16; i += 256) {
    int kk = i >> 4, q = i & 15;
    d4[i] = *(const float4*)(hb + (size_t)kk * NPT + q * 4);
  }
  for (int i = tid; i < NC * 64; i += 256) ((float4*)w3l)[i] = ((const float4*)w3)[i];
  __syncthreads();
  int p = tid & 63, og = tid >> 6;
  int pix = (int)pidx[b * NPT + p0 + p];
  for (int o = og; o < NC; o += 4) {
    float acc = 0.f;
    #pragma unroll 8
    for (int kk = 0; kk < 256; kk++) acc += w3l[o * 256 + kk] * h2l[kk][p];
    out[(((size_t)b * NC + o) << 15) + pix] = acc + b3[o];
  }
}

// ----------------------------------------------------------------
extern "C" void kernel_launch(void* const* d_in, const int* in_sizes, int n_in,
                              void* d_out, int out_size, void* d_ws, size_t ws_size,
                              hipStream_t stream) {
  const float* coarse = (const float*)d_in[0];
  const float* fine   = (const float*)d_in[1];
  const float* w1 = (const float*)d_in[2];
  const float* b1 = (const float*)d_in[3];
  const float* w2 = (const float*)d_in[4];
  const float* b2 = (const float*)d_in[5];
  const float* w3 = (const float*)d_in[6];
  const float* b3 = (const float*)d_in[7];
  float* out = (float*)d_out;
  char* ws = (char*)d_ws;
  // workspace layout (bytes):
  float*    unc   = (float*)ws;                       // 1,048,576
  unsigned* pidx  = (unsigned*)(ws + 1048576);        //    65,536
  int*      hist1 = (int*)(ws + 1114112);             //    65,536
  int*      hist2 = (int*)(ws + 1179648);             //    65,536
  int*      hist3 = (int*)(ws + 1245184);             //    32,768
  int*      cnts  = (int*)(ws + 1277952);             //     1,024 (g_cnt[8], e_cnt[8], keq[8])
  int*      eq    = (int*)(ws + 1278976);             //   131,072
  float*    w1T   = (float*)(ws + 1410048);           //   286,720 (KPAD x 256)
  float*    w2T   = (float*)(ws + 1696768);           //   262,144
  float*    pfT   = (float*)(ws + 1958912);           // 18,350,080 (8 x KPAD x 2048)
  float*    h1T   = (float*)(ws + 20308992);          // 16,777,216
  float*    h2T   = pfT;                              // pf dead after layer 1

  hipMemsetAsync(ws + 1114112, 0, 164864, stream);    // hist1..cnts
  k_upsample_uncert<<<dim3(NB * HW / 256), 256, 0, stream>>>(coarse, out, unc);
  k_transpose<<<dim3((KPAD * HID + HID * HID + 255) / 256), 256, 0, stream>>>(w1, w2, w1T, w2T);
  k_hist1<<<dim3(NB, 16), 256, 0, stream>>>(unc, hist1);
  k_hist2<<<dim3(NB, 16), 256, 0, stream>>>(unc, hist1, hist2);
  k_hist3<<<dim3(NB, 16), 256, 0, stream>>>(unc, hist1, hist2, hist3);
  k_select<<<dim3(NB, 16), 256, 0, stream>>>(unc, hist1, hist2, hist3, cnts, eq, pidx);
  k_ties<<<dim3(NB), 256, 0, stream>>>(cnts, eq, pidx);
  k_gather<<<dim3(KPAD, NB, 2), 256, 0, stream>>>(fine, out, pidx, pfT);
  k_gemm<KPAD, true><<<dim3(16, 2, NB), 256, 0, stream>>>(w1T, b1, pfT, h1T);
  k_gemm<HID, true><<<dim3(16, 2, NB), 256, 0, stream>>>(w2T, b2, h1T, h2T);
  k_mlp3_scatter<<<dim3(NPT / 64, NB), 256, 0, stream>>>(w3, b3, h2T, pidx, out);
}